// Round 1
// baseline (420.051 us; speedup 1.0000x reference)
//
#include <hip/hip_runtime.h>
#include <hip/hip_bf16.h>
#include <stdint.h>

typedef unsigned short u16;
typedef __bf16 bf16x8 __attribute__((ext_vector_type(8)));
typedef float f32x4 __attribute__((ext_vector_type(4)));
typedef unsigned short u16x8 __attribute__((ext_vector_type(8)));

#define QEPS 1e-8f

// round-to-nearest-even f32 -> bf16
__device__ __forceinline__ u16 f32_to_bf16_rne(float f) {
    uint32_t u = __float_as_uint(f);
    u += 0x7fffu + ((u >> 16) & 1u);
    return (u16)(u >> 16);
}

// ---------------- x: f32 -> bf16, [M][K] row-major ----------------
__global__ void cvt_x_bf16(const float* __restrict__ x, u16* __restrict__ xb, int n8) {
    int idx = blockIdx.x * blockDim.x + threadIdx.x;
    if (idx >= n8) return;
    const float4* p = (const float4*)(x + (size_t)idx * 8);
    float4 a = p[0], b = p[1];
    u16x8 r;
    r[0] = f32_to_bf16_rne(a.x); r[1] = f32_to_bf16_rne(a.y);
    r[2] = f32_to_bf16_rne(a.z); r[3] = f32_to_bf16_rne(a.w);
    r[4] = f32_to_bf16_rne(b.x); r[5] = f32_to_bf16_rne(b.y);
    r[6] = f32_to_bf16_rne(b.z); r[7] = f32_to_bf16_rne(b.w);
    *(u16x8*)(xb + (size_t)idx * 8) = r;
}

// ------- weight dequant: w_dq[n][k] = round(w/s)*s, bf16, [N][K] (B^T layout) -------
__global__ void dequant_w_bf16(const float* __restrict__ w, const float* __restrict__ ss,
                               u16* __restrict__ wb, int N, int K) {
    int idx = blockIdx.x * blockDim.x + threadIdx.x;   // one thread per 8 consecutive k
    int pr = K >> 3;
    if (idx >= N * pr) return;
    int n = idx / pr;
    int k8 = (idx - n * pr) << 3;
    // group index: k8/128 (8 consecutive k never straddle a 128-group)
    float s = ss[(size_t)(k8 >> 7) * N + n] + QEPS;
    const float4* p = (const float4*)(w + (size_t)n * K + k8);
    float4 a = p[0], b = p[1];
    float v[8] = {a.x, a.y, a.z, a.w, b.x, b.y, b.z, b.w};
    u16x8 r;
#pragma unroll
    for (int i = 0; i < 8; ++i) {
        float q = rintf(v[i] / s);      // IEEE f32 div + RNE round == jnp f32 semantics
        r[i] = f32_to_bf16_rne(q * s);
    }
    *(u16x8*)(wb + (size_t)n * K + k8) = r;
}

// ---------------- GEMM: C[M][N] = A[M][K](bf16) * B[N][K]^T(bf16) + bias ----------------
#define BM 128
#define BN 128
#define BK 32

#define ASYNC_COPY16(g, l)                                                                 \
    __builtin_amdgcn_global_load_lds((const __attribute__((address_space(1))) void*)(g),   \
                                     (__attribute__((address_space(3))) void*)(l), 16, 0, 0)

__global__ __launch_bounds__(256) void gemm_bf16_bt(
        const u16* __restrict__ A,    // [M][K] bf16
        const u16* __restrict__ B,    // [N][K] bf16
        const float* __restrict__ bias,
        float* __restrict__ C,        // [M][N] f32
        int M, int N, int K) {
    __shared__ __align__(16) u16 sA[BM * BK];   // 8 KiB, linear (global_load_lds dest)
    __shared__ __align__(16) u16 sB[BN * BK];   // 8 KiB

    const int tid  = threadIdx.x;
    const int wave = tid >> 6;
    const int lane = tid & 63;

    // XCD-aware bijective swizzle (grid is a multiple of 8)
    const int nwg = gridDim.x;
    const int cpx = nwg >> 3;
    const int bid = blockIdx.x;
    const int swz = (bid & 7) * cpx + (bid >> 3);
    const int nbn = N / BN;
    const int bm  = swz / nbn;
    const int bn  = swz - bm * nbn;

    const int wr = wave >> 1;   // wave row (0..1) -> 64 rows
    const int wc = wave & 1;    // wave col (0..1) -> 64 cols

    // staging: chunk c = {wave, wave+4}; chunk c covers tile rows [c*16, c*16+16)
    // lane l handles LDS bytes [c*1024 + l*16, +16) == row c*16 + (l>>2), col (l&3)*8
    const int srow = (wave << 4) + (lane >> 2);
    const int scol = (lane & 3) << 3;
    const u16* gA0 = A + (size_t)(bm * BM + srow) * K + scol;
    const u16* gA1 = gA0 + (size_t)64 * K;
    const u16* gB0 = B + (size_t)(bn * BN + srow) * K + scol;
    const u16* gB1 = gB0 + (size_t)64 * K;
    char* ldsA0 = (char*)sA + (wave << 10);
    char* ldsA1 = (char*)sA + ((wave + 4) << 10);
    char* ldsB0 = (char*)sB + (wave << 10);
    char* ldsB1 = (char*)sB + ((wave + 4) << 10);

    // fragment read base: row = wr*64 + (lane&15) (+m*16), k = (lane>>4)*8
    const u16* pa = sA + ((size_t)((wr << 6) + (lane & 15))) * BK + ((lane >> 4) << 3);
    const u16* pb = sB + ((size_t)((wc << 6) + (lane & 15))) * BK + ((lane >> 4) << 3);

    f32x4 acc[4][4] = {};

    for (int kt = 0; kt < K; kt += BK) {
        __syncthreads();                 // previous tile's reads done
        ASYNC_COPY16(gA0 + kt, ldsA0);
        ASYNC_COPY16(gA1 + kt, ldsA1);
        ASYNC_COPY16(gB0 + kt, ldsB0);
        ASYNC_COPY16(gB1 + kt, ldsB1);
        __syncthreads();                 // vmcnt(0) drain + barrier: tile visible

        bf16x8 af[4], bf[4];
#pragma unroll
        for (int m = 0; m < 4; ++m) af[m] = *(const bf16x8*)(pa + m * 16 * BK);
#pragma unroll
        for (int n = 0; n < 4; ++n) bf[n] = *(const bf16x8*)(pb + n * 16 * BK);
#pragma unroll
        for (int m = 0; m < 4; ++m)
#pragma unroll
            for (int n = 0; n < 4; ++n)
                acc[m][n] = __builtin_amdgcn_mfma_f32_16x16x32_bf16(af[m], bf[n], acc[m][n], 0, 0, 0);
    }

    // epilogue: C/D layout row=(lane>>4)*4+i, col=lane&15  [m89-verified]
    const int r0 = bm * BM + (wr << 6) + ((lane >> 4) << 2);
    const int c0 = bn * BN + (wc << 6) + (lane & 15);
    float bv[4];
#pragma unroll
    for (int n = 0; n < 4; ++n) bv[n] = bias[c0 + n * 16];
#pragma unroll
    for (int m = 0; m < 4; ++m)
#pragma unroll
        for (int n = 0; n < 4; ++n)
#pragma unroll
            for (int i = 0; i < 4; ++i)
                C[(size_t)(r0 + (m << 4) + i) * N + (c0 + (n << 4))] = acc[m][n][i] + bv[n];
}

extern "C" void kernel_launch(void* const* d_in, const int* in_sizes, int n_in,
                              void* d_out, int out_size, void* d_ws, size_t ws_size,
                              hipStream_t stream) {
    const float* x    = (const float*)d_in[0];   // [B,S,K] f32
    const float* w    = (const float*)d_in[1];   // [N,K]   f32
    const float* bias = (const float*)d_in[2];   // [N]     f32
    const float* ss   = (const float*)d_in[3];   // [K/128, N] f32
    float* out        = (float*)d_out;           // [B,S,N] f32

    const int N = in_sizes[2];            // 4096
    const int K = in_sizes[1] / N;        // 4096
    const int M = in_sizes[0] / K;        // 8192

    u16* xb = (u16*)d_ws;                       // [M][K] bf16
    u16* wb = xb + (size_t)M * K;               // [N][K] bf16

    int n8x = (M * K) >> 3;
    cvt_x_bf16<<<(n8x + 255) / 256, 256, 0, stream>>>(x, xb, n8x);

    int n8w = (N * K) >> 3;
    dequant_w_bf16<<<(n8w + 255) / 256, 256, 0, stream>>>(w, ss, wb, N, K);

    dim3 grid((M / BM) * (N / BN));      // 64*32 = 2048, %8 == 0
    gemm_bf16_bt<<<grid, 256, 0, stream>>>(xb, wb, bias, out, M, N, K);
}

// Round 2
// 281.315 us; speedup vs baseline: 1.4932x; 1.4932x over previous
//
#include <hip/hip_runtime.h>
#include <hip/hip_bf16.h>
#include <stdint.h>

typedef unsigned short u16;
typedef __bf16 bf16x8 __attribute__((ext_vector_type(8)));
typedef float f32x4 __attribute__((ext_vector_type(4)));
typedef unsigned short u16x8 __attribute__((ext_vector_type(8)));

#define QEPS 1e-8f

// round-to-nearest-even f32 -> bf16
__device__ __forceinline__ u16 f32_to_bf16_rne(float f) {
    uint32_t u = __float_as_uint(f);
    u += 0x7fffu + ((u >> 16) & 1u);
    return (u16)(u >> 16);
}

// ---------------- x: f32 -> bf16, [M][K] row-major ----------------
__global__ void cvt_x_bf16(const float* __restrict__ x, u16* __restrict__ xb, int n8) {
    int idx = blockIdx.x * blockDim.x + threadIdx.x;
    if (idx >= n8) return;
    const float4* p = (const float4*)(x + (size_t)idx * 8);
    float4 a = p[0], b = p[1];
    u16x8 r;
    r[0] = f32_to_bf16_rne(a.x); r[1] = f32_to_bf16_rne(a.y);
    r[2] = f32_to_bf16_rne(a.z); r[3] = f32_to_bf16_rne(a.w);
    r[4] = f32_to_bf16_rne(b.x); r[5] = f32_to_bf16_rne(b.y);
    r[6] = f32_to_bf16_rne(b.z); r[7] = f32_to_bf16_rne(b.w);
    *(u16x8*)(xb + (size_t)idx * 8) = r;
}

// ------- weight dequant: w_dq[n][k] = round(w/s)*s, bf16, [N][K] (B^T layout) -------
__global__ void dequant_w_bf16(const float* __restrict__ w, const float* __restrict__ ss,
                               u16* __restrict__ wb, int N, int K) {
    int idx = blockIdx.x * blockDim.x + threadIdx.x;   // one thread per 8 consecutive k
    int pr = K >> 3;
    if (idx >= N * pr) return;
    int n = idx / pr;
    int k8 = (idx - n * pr) << 3;
    float s = ss[(size_t)(k8 >> 7) * N + n] + QEPS;
    const float4* p = (const float4*)(w + (size_t)n * K + k8);
    float4 a = p[0], b = p[1];
    float v[8] = {a.x, a.y, a.z, a.w, b.x, b.y, b.z, b.w};
    u16x8 r;
#pragma unroll
    for (int i = 0; i < 8; ++i) {
        float q = rintf(v[i] / s);
        r[i] = f32_to_bf16_rne(q * s);
    }
    *(u16x8*)(wb + (size_t)n * K + k8) = r;
}

// ======================= 256x256 pipelined bf16 GEMM =======================
// C[M][N] = A[M][K] * B[N][K]^T + bias.  BK=32, 8 waves (2x4), per-wave 128x64.
// 4 LDS buffers (depth-3 prefetch), counted vmcnt, swizzled LDS via pre-swizzled
// global source (rule 21: linear gload_lds dest + inverse-swz source + swz read).
#define BM 256
#define BN 256
#define BK 32
#define BUFB 32768      // bytes per buffer: A 16K + B 16K
#define ABYT 16384      // A region bytes within buffer
#define LDSB 131072     // 4 buffers

#define ASYNC16(g, l)                                                                      \
    __builtin_amdgcn_global_load_lds((const __attribute__((address_space(1))) void*)(g),   \
                                     (__attribute__((address_space(3))) void*)(l), 16, 0, 0)
#define VMCNT(n) asm volatile("s_waitcnt vmcnt(" #n ")" ::: "memory")

__global__ __launch_bounds__(512, 2) void gemm_bf16_bt_256(
        const u16* __restrict__ A,    // [M][K] bf16
        const u16* __restrict__ B,    // [N][K] bf16
        const float* __restrict__ bias,
        float* __restrict__ C,        // [M][N] f32
        int M, int N, int K) {
    extern __shared__ char lds[];
    const int tid  = threadIdx.x;
    const int wave = tid >> 6;
    const int lane = tid & 63;

    // XCD-aware bijective swizzle (grid 512, %8==0)
    const int nwg = gridDim.x;
    const int cpx = nwg >> 3;
    const int bid = blockIdx.x;
    const int swz = (bid & 7) * cpx + (bid >> 3);
    const int nbn = N / BN;                  // 16
    const int bm  = swz / nbn;
    const int bn  = swz - bm * nbn;

    const int wr = wave >> 2;                // 0..1 -> 128 rows
    const int wc = wave & 3;                 // 0..3 -> 64 cols

    // ---- staging: per K-tile 4 x global_load_lds (2 rounds A, 2 rounds B) ----
    // linear LDS layout [row][32k] bf16 (64 B rows); source k pre-swizzled by
    // kb ^= ((row>>1)&3)<<4  (involution, stays inside the 64-B row window)
    const int srow  = tid >> 2;                                        // 0..127
    const int kbsrc = ((tid & 3) << 4) ^ (((tid >> 3) & 3) << 4);
    const char* gA0 = (const char*)A + ((size_t)(bm * BM + srow) * K) * 2 + kbsrc;
    const char* gA1 = (const char*)A + ((size_t)(bm * BM + 128 + srow) * K) * 2 + kbsrc;
    const char* gB0 = (const char*)B + ((size_t)(bn * BN + srow) * K) * 2 + kbsrc;
    const char* gB1 = (const char*)B + ((size_t)(bn * BN + 128 + srow) * K) * 2 + kbsrc;
    char* ldsw = lds + (wave << 10);         // wave-uniform base; HW adds lane*16

    auto STAGE = [&](int t) {
        const size_t ko = (size_t)t << 6;    // t * 32 k * 2 B
        char* d = ldsw + ((t & 3) * BUFB);
        ASYNC16(gA0 + ko, d);
        ASYNC16(gA1 + ko, d + 8192);
        ASYNC16(gB0 + ko, d + ABYT);
        ASYNC16(gB1 + ko, d + ABYT + 8192);
    };

    // ---- fragment reads: same XOR on the read address ----
    const int kx = ((lane >> 4) ^ ((lane >> 1) & 3)) << 4;
    const char* pa = lds + (size_t)(wr * 128 + (lane & 15)) * 64 + kx;
    const char* pb = lds + ABYT + (size_t)(wc * 64 + (lane & 15)) * 64 + kx;

    f32x4 acc[8][4] = {};

    auto COMPUTE = [&](int t) {
        const int bo = (t & 3) * BUFB;
        bf16x8 bfr[4], af[8];
#pragma unroll
        for (int n = 0; n < 4; ++n) bfr[n] = *(const bf16x8*)(pb + bo + n * 1024);
#pragma unroll
        for (int m = 0; m < 8; ++m) af[m] = *(const bf16x8*)(pa + bo + m * 1024);
        __builtin_amdgcn_s_setprio(1);
#pragma unroll
        for (int m = 0; m < 8; ++m)
#pragma unroll
            for (int n = 0; n < 4; ++n)
                acc[m][n] = __builtin_amdgcn_mfma_f32_16x16x32_bf16(af[m], bfr[n], acc[m][n], 0, 0, 0);
        __builtin_amdgcn_s_setprio(0);
    };

    const int NT = K >> 5;                   // 128

    // prologue: tiles 0,1,2 in flight; confirm tile 0 (own loads) then barrier
    STAGE(0); STAGE(1); STAGE(2);
    VMCNT(8);
    __builtin_amdgcn_s_barrier();

    for (int t = 0; t < NT - 3; ++t) {
        STAGE(t + 3);                        // overwrites tile t-1's buffer (safe: consumed before last barrier)
        COMPUTE(t);
        VMCNT(8);                            // tile t+1 resident (tiles t+2,t+3 stay in flight)
        __builtin_amdgcn_s_barrier();
    }
    COMPUTE(NT - 3); VMCNT(4); __builtin_amdgcn_s_barrier();
    COMPUTE(NT - 2); VMCNT(0); __builtin_amdgcn_s_barrier();
    COMPUTE(NT - 1);

    // ---- epilogue: C/D layout row=(lane>>4)*4+i, col=lane&15 ----
    const int r0 = bm * BM + wr * 128 + ((lane >> 4) << 2);
    const int c0 = bn * BN + wc * 64 + (lane & 15);
    float bv[4];
#pragma unroll
    for (int n = 0; n < 4; ++n) bv[n] = bias[c0 + n * 16];
#pragma unroll
    for (int m = 0; m < 8; ++m)
#pragma unroll
        for (int n = 0; n < 4; ++n)
#pragma unroll
            for (int i = 0; i < 4; ++i)
                C[(size_t)(r0 + m * 16 + i) * N + (c0 + n * 16)] = acc[m][n][i] + bv[n];
}

extern "C" void kernel_launch(void* const* d_in, const int* in_sizes, int n_in,
                              void* d_out, int out_size, void* d_ws, size_t ws_size,
                              hipStream_t stream) {
    const float* x    = (const float*)d_in[0];   // [B,S,K] f32
    const float* w    = (const float*)d_in[1];   // [N,K]   f32
    const float* bias = (const float*)d_in[2];   // [N]     f32
    const float* ss   = (const float*)d_in[3];   // [K/128, N] f32
    float* out        = (float*)d_out;           // [B,S,N] f32

    const int N = in_sizes[2];            // 4096
    const int K = in_sizes[1] / N;        // 4096
    const int M = in_sizes[0] / K;        // 8192

    u16* xb = (u16*)d_ws;                        // [M][K] bf16
    u16* wb = xb + (size_t)M * K;                // [N][K] bf16

    int n8x = (M * K) >> 3;
    cvt_x_bf16<<<(n8x + 255) / 256, 256, 0, stream>>>(x, xb, n8x);

    int n8w = (N * K) >> 3;
    dequant_w_bf16<<<(n8w + 255) / 256, 256, 0, stream>>>(w, ss, wb, N, K);

    (void)hipFuncSetAttribute((const void*)gemm_bf16_bt_256,
                              hipFuncAttributeMaxDynamicSharedMemorySize, LDSB);
    dim3 grid((M / BM) * (N / BN));              // 32*16 = 512, %8 == 0
    gemm_bf16_bt_256<<<grid, 512, LDSB, stream>>>(xb, wb, bias, out, M, N, K);
}